// Round 14
// baseline (2566.719 us; speedup 1.0000x reference)
//
#include <hip/hip_runtime.h>

// ============================================================================
// Bidirectional LSTM (Keras-style), B=64 T=256 I=512 H=800, fp32 in/out.
//   K0  pack W/U -> bf16 MFMA B-fragment layout
//   K1  kproj: input projections (both dirs, bias folded), bf16 MFMA, row
//       layout [b][t][j*4+g]; proj_f ALIASED into d_out Hcat region.
//       NEW: block = (d,b,tt,jj) covering ALL 4 gates -- raw x staged ONCE
//       (4x fewer x reads: 1.34 GB -> 335 MB). Mask in {0,2} exactly
//       (RATE=0.5): apply as binary AND on A-fragments, scale acc*2 in
//       epilogue -- bit-identical to staging bf16(x*mask).
//   K2  krecur: BYTE-IDENTICAL to rounds 11/12/13 (proven 1445 us, VGPR 192).
// ============================================================================

#define TDIM 256
#define IDIM 512
#define HDIM 800
#define H4   3200

typedef __bf16 bf16;
typedef __bf16 bf16x8 __attribute__((ext_vector_type(8)));
typedef __bf16 bf16x4 __attribute__((ext_vector_type(4)));
typedef float  f32x4  __attribute__((ext_vector_type(4)));
typedef unsigned int   u32x4 __attribute__((ext_vector_type(4)));
typedef unsigned int   u32x2 __attribute__((ext_vector_type(2)));
typedef unsigned short u16x8 __attribute__((ext_vector_type(8)));

// workspace layout (bytes)
#define OFF_UPK   0ull            // 2*200*25*512 bf16 = 10,240,000
#define OFF_WPK   10240000ull     // 2*200*16*512 bf16 =  6,553,600
#define OFF_PROJB 16793600ull     // 64*256*3200 bf16  = 104,857,600
#define OFF_HA    121651200ull    // 257 slots * 204,800 B = 52,633,600
#define OFF_FLAGS 174284800ull    // 400 wave-flags * 32 B + epochs at int 3200..3207
#define WS_NEED   174297664ull    // = OFF_FLAGS + 12832 (12800 flags + 32 epochs)

__device__ __forceinline__ float sigf(float x)   { return 1.0f / (1.0f + __expf(-x)); }
__device__ __forceinline__ float tanhf_f(float x){ return 2.0f / (1.0f + __expf(-2.0f*x)) - 1.0f; }

__device__ __forceinline__ void store_b128_sc1(void* p, u32x4 v) {
    asm volatile("global_store_dwordx4 %0, %1, off sc1" :: "v"(p), "v"(v) : "memory");
}

// ---------------------------------------------------------------------------
// zero-init hA slot 0 (12,800 uint4) + flags/epochs (802 uint4)
__global__ __launch_bounds__(256) void kinit(uint4* __restrict__ ha0,
                                             uint4* __restrict__ flg) {
    int idx = blockIdx.x * 256 + threadIdx.x;
    if (idx < 12800) ha0[idx] = uint4{0u, 0u, 0u, 0u};
    else if (idx < 13602) flg[idx - 12800] = uint4{0u, 0u, 0u, 0u};
}

// ---------------------------------------------------------------------------
// pack fp32 [K][3200] weights into bf16 B-fragment tiles:
// tile (d, nt, kt): lane l holds S[kt*32 + (l>>4)*8 + j][nt*16 + (l&15)], j=0..7
__global__ __launch_bounds__(64) void kpack(const float* __restrict__ Sf,
                                            const float* __restrict__ Sb,
                                            bf16* __restrict__ dst, int nkt) {
    int bx = blockIdx.x;
    int kt = bx % nkt; int rest = bx / nkt;
    int nt = rest % 200; int d = rest / 200;
    const float* S = d ? Sb : Sf;
    int l  = threadIdx.x;
    int n  = nt * 16 + (l & 15);
    int k0 = kt * 32 + (l >> 4) * 8;
    bf16x8 v;
#pragma unroll
    for (int j = 0; j < 8; ++j) v[j] = (bf16)S[(size_t)(k0 + j) * H4 + n];
    *(bf16x8*)(dst + ((size_t)bx * 64 + l) * 8) = v;
}

// ---------------------------------------------------------------------------
// K1: proj row layout [b][t][j*4 + g], j in [0,800), g in [0,4).
// t_eff = s (fwd) or 255-s (bwd).
// grid: d*1280 + b*20 + tt*5 + jj  (2560 blocks; block covers all 4 gates)
// Mask trick (RATE=0.5 => mask in {0,2.0}): stage RAW bf16 x; per gate AND
// the A-fragment with a binary mask (0x0000/0xFFFF per element) and multiply
// the fp32 accumulator by 2 in the epilogue. Bit-identical to staging
// bf16(x*mask): *2 is an exact exponent shift commuting with RNE.
#define K1ROW 520
__global__ __launch_bounds__(256, 1) void kproj(
    const float* __restrict__ x, const float* __restrict__ mf, const float* __restrict__ mb,
    const bf16* __restrict__ wpk, const float* __restrict__ biasf, const float* __restrict__ biasb,
    bf16* __restrict__ projf, bf16* __restrict__ projb) {
    __shared__ bf16 sA[64 * K1ROW];
    __shared__ unsigned short sM[4][512];   // binary masks, 4 gates x 512

    int bx = blockIdx.x;
    int jj = bx % 5; int tt = (bx / 5) & 3;
    int b  = (bx / 20) & 63; int d = bx / 1280;

    int t  = threadIdx.x;
    int wv = t >> 6, l = t & 63;
    int k  = l * 8;

    // stage raw x tile (64 rows x 512), bf16, no mask
    for (int it = 0; it < 16; ++it) {
        int trow = it * 4 + wv;
        int tg   = tt * 64 + trow;
        int te   = d ? (255 - tg) : tg;
        const float* xs = x + ((size_t)b * TDIM + te) * IDIM + k;
        float4 x0 = *(const float4*)xs;
        float4 x1 = *(const float4*)(xs + 4);
        bf16x8 v;
        v[0] = (bf16)x0.x; v[1] = (bf16)x0.y; v[2] = (bf16)x0.z; v[3] = (bf16)x0.w;
        v[4] = (bf16)x1.x; v[5] = (bf16)x1.y; v[6] = (bf16)x1.z; v[7] = (bf16)x1.w;
        *(bf16x8*)(&sA[trow * K1ROW + k]) = v;
    }

    // stage binary masks: thread t covers gate wv, elements k..k+8
    {
        const float* mk = (d ? mb : mf) + (size_t)(b * 4 + wv) * IDIM + k;
        float4 a0 = *(const float4*)mk;
        float4 a1 = *(const float4*)(mk + 4);
        u16x8 mv;
        mv[0] = (a0.x != 0.f) ? 0xFFFFu : 0u; mv[1] = (a0.y != 0.f) ? 0xFFFFu : 0u;
        mv[2] = (a0.z != 0.f) ? 0xFFFFu : 0u; mv[3] = (a0.w != 0.f) ? 0xFFFFu : 0u;
        mv[4] = (a1.x != 0.f) ? 0xFFFFu : 0u; mv[5] = (a1.y != 0.f) ? 0xFFFFu : 0u;
        mv[6] = (a1.z != 0.f) ? 0xFFFFu : 0u; mv[7] = (a1.w != 0.f) ? 0xFFFFu : 0u;
        *(u16x8*)(&sM[wv][k]) = mv;
    }
    __syncthreads();

    const float* bias = d ? biasb : biasf;
    bf16* dst = d ? projb : projf;
    int row0 = tt * 64 + wv * 16 + ((l >> 4) * 4);

#pragma unroll 1
    for (int g = 0; g < 4; ++g) {
        f32x4 acc[10];
#pragma unroll
        for (int nt = 0; nt < 10; ++nt) acc[nt] = f32x4{0.f, 0.f, 0.f, 0.f};

        int NTbase = g * 50 + jj * 10;
        const bf16* wb = wpk + ((size_t)d * 200 + NTbase) * 16 * 512 + l * 8;
        for (int kt = 0; kt < 16; ++kt) {
            u32x4 ar = *(const u32x4*)(&sA[(wv * 16 + (l & 15)) * K1ROW + kt * 32 + (l >> 4) * 8]);
            u32x4 mr = *(const u32x4*)(&sM[g][kt * 32 + (l >> 4) * 8]);
            bf16x8 a = __builtin_bit_cast(bf16x8, ar & mr);
#pragma unroll
            for (int nt = 0; nt < 10; ++nt) {
                bf16x8 bw = *(const bf16x8*)(wb + ((size_t)nt * 16 + kt) * 512);
                acc[nt] = __builtin_amdgcn_mfma_f32_16x16x32_bf16(a, bw, acc[nt], 0, 0, 0);
            }
        }

#pragma unroll
        for (int nt = 0; nt < 10; ++nt) {
            int jr = jj * 160 + nt * 16 + (l & 15);
            float bv = bias[g * HDIM + jr];
#pragma unroll
            for (int r = 0; r < 4; ++r) {
                int trow = row0 + r;
                dst[((size_t)b * TDIM + trow) * H4 + (size_t)jr * 4 + g] =
                    (bf16)(acc[nt][r] * 2.0f + bv);
            }
        }
    }
}

// ---------------------------------------------------------------------------
// K2: persistent recurrence. grid = 100 x 256 (d = bx/50, jt = bx%50).
// Wave w (= mt) owns batch rows [w*16, w*16+16).
// hA slot layout: [slot][d][chunk=kt*4+mt][lane(64)][8] bf16 (A-fragment packed)
// flags: per (block, wave): flags[(bx*4 + w)*8] (max index 3192).
// epochs: flags[3200 + w] (fwd class-w), flags[3204 + w] (bwd class-w),
// published by the jt==0 block of each direction on its own gate-exit.
__global__ __launch_bounds__(256, 1) void krecur(
    const bf16* __restrict__ upk,
    const bf16* __restrict__ projf, const bf16* __restrict__ projb,
    bf16* __restrict__ hA, int* __restrict__ flags,
    float* __restrict__ out) {
    extern __shared__ char ldsraw[];
    bf16* uLds = (bf16*)ldsraw;        // gates 2,3: [2][25 kt][64 lane][8] = 51,200 B
    __shared__ bf16 sh2[4][16][24];    // per-wave h transpose (pad 24)

    int bx = blockIdx.x;
    int jt = bx % 50; int d = bx / 50;
    int tid = threadIdx.x;
    int w  = tid >> 6;                 // wave index == batch tile mt
    int l  = tid & 63;
    int lm = l & 15, q = l >> 4;
    int j0 = jt * 16;
    int jcol = j0 + lm;
    int kt0 = jt >> 1, qbase = (jt & 1) * 2;

    // ---- U gates 0,1 -> registers (asm-opaque: compiler cannot rematerialize)
    bf16x8 ureg[50];
#pragma unroll
    for (int g = 0; g < 2; ++g)
#pragma unroll
        for (int kt = 0; kt < 25; ++kt) {
            bf16x8 v = *(const bf16x8*)(
                upk + (((size_t)(d * 200 + g * 50 + jt)) * 25 + kt) * 512 + (size_t)l * 8);
            u32x4 u = __builtin_bit_cast(u32x4, v);
            asm volatile("" : "+v"(u));        // pin as opaque register value
            ureg[g * 25 + kt] = __builtin_bit_cast(bf16x8, u);
        }

    // ---- U gates 2,3 -> LDS (waves 0,1 stage; one-time)
    if (w < 2) {
        const bf16* ug = upk + (((size_t)(d * 200 + (w + 2) * 50 + jt)) * 25) * 512 + (size_t)l * 8;
        bf16* udst = uLds + (size_t)w * 25 * 512 + (size_t)l * 8;
#pragma unroll
        for (int kt = 0; kt < 25; ++kt) {
            bf16x8 v = *(const bf16x8*)(ug + (size_t)kt * 512);
            *(bf16x8*)(udst + (size_t)kt * 512) = v;
        }
    }
    __syncthreads();

    const char* prbase = (const char*)(d ? projb : projf);

    bool isAgg = (jt == 0);            // one aggregator block per direction
    int epOwn = 3200 + d * 4 + w;      // epoch line this block publishes (if agg)
    int f1, f2;
    int fi1, fi2;
    if (isAgg) {
        // aggregators direct-poll the flag lines (round-5 scheme)
        if (d == 0) { f1 = (l < 50) ? l : 49; f2 = f1; }      // fwd: 50 lines
        else        { f1 = l; f2 = (l < 36) ? (64 + l) : l; } // bwd: all 100
        fi1 = (f1 * 4 + w) * 8;
        fi2 = (f2 * 4 + w) * 8;
    } else {
        // consumers poll only the epoch line (wave-uniform, 1 cache line)
        fi1 = 3200 + w;                            // fwd epoch (h dep / alias guard)
        fi2 = (d == 0) ? (3200 + w) : (3204 + w);  // own-direction epoch
    }
    int myflag = (bx * 4 + w) * 8;

    float hprev[4], cst[4];
#pragma unroll
    for (int r = 0; r < 4; ++r) { hprev[r] = 0.f; cst[r] = 0.f; }

    size_t prOff = (size_t)j0 * 8 + (size_t)lm * 8;

#pragma unroll 1
    for (int s = 0; s < 256; ++s) {
        // 1. proj(s) loads for this wave's rows (nt; issued pre-gate, long slack)
        u32x2 pr[4];
#pragma unroll
        for (int r = 0; r < 4; ++r) {
            int b = w * 16 + q * 4 + r;
            pr[r] = __builtin_nontemporal_load(
                (const u32x2*)(prbase + ((size_t)b * TDIM + s) * 6400 + prOff));
        }

        // 2. spin until deps reach s (aggregator: flag lines; consumer: epochs)
        if (s > 0) {
            for (;;) {
                int a  = __hip_atomic_load(flags + fi1, __ATOMIC_RELAXED, __HIP_MEMORY_SCOPE_AGENT);
                int b2 = __hip_atomic_load(flags + fi2, __ATOMIC_RELAXED, __HIP_MEMORY_SCOPE_AGENT);
                if (__all((a >= s) && (b2 >= s))) break;
                __builtin_amdgcn_s_sleep(1);   // light backoff
            }
            if (isAgg && l == 0)               // publish class-w epoch
                __hip_atomic_store(flags + epOwn, s, __ATOMIC_RELAXED, __HIP_MEMORY_SCOPE_AGENT);
        }
        asm volatile("" ::: "memory");         // order af loads after spin-exit

        // 3. h A-fragments, chunks (kt, w): issue all 25 loads up front
        const bf16* hin = hA + (size_t)s * 102400 + (size_t)d * 51200
                             + (size_t)w * 512 + (size_t)l * 8;
        bf16x8 af[25];
#pragma unroll
        for (int kt = 0; kt < 25; ++kt)
            af[kt] = *(const bf16x8*)(hin + (size_t)kt * 2048);

        // 4. delayed Hcat write: row s-1 (nt streaming; after af issue)
        if (s > 0) {
#pragma unroll
            for (int r = 0; r < 4; ++r) {
                int b = w * 16 + q * 4 + r;
                __builtin_nontemporal_store(hprev[r],
                    &out[((size_t)b * TDIM + (s - 1)) * 1600 + d * HDIM + jcol]);
            }
        }

        // 5. MFMA: gates 0,1 B from registers; gates 2,3 B from LDS
        f32x4 acc[4];
#pragma unroll
        for (int g = 0; g < 4; ++g) acc[g] = f32x4{0.f, 0.f, 0.f, 0.f};

        const bf16* ul = uLds + (size_t)l * 8;
#pragma unroll
        for (int kt = 0; kt < 25; ++kt) {
            acc[0] = __builtin_amdgcn_mfma_f32_16x16x32_bf16(af[kt], ureg[kt],      acc[0], 0, 0, 0);
            acc[1] = __builtin_amdgcn_mfma_f32_16x16x32_bf16(af[kt], ureg[25 + kt], acc[1], 0, 0, 0);
            bf16x8 b2 = *(const bf16x8*)(ul + (size_t)kt * 512);
            bf16x8 b3 = *(const bf16x8*)(ul + (size_t)(25 + kt) * 512);
            acc[2] = __builtin_amdgcn_mfma_f32_16x16x32_bf16(af[kt], b2, acc[2], 0, 0, 0);
            acc[3] = __builtin_amdgcn_mfma_f32_16x16x32_bf16(af[kt], b3, acc[3], 0, 0, 0);
        }

        // 6. gates + state update; h -> per-wave LDS transpose
#pragma unroll
        for (int r = 0; r < 4; ++r) {
            bf16x4 p4 = __builtin_bit_cast(bf16x4, pr[r]);
            float zi = acc[0][r] + (float)p4[0];
            float zf = acc[1][r] + (float)p4[1];
            float zg = acc[2][r] + (float)p4[2];
            float zo = acc[3][r] + (float)p4[3];
            float ig = sigf(zi), fg = sigf(zf), gg = tanhf_f(zg), og = sigf(zo);
            float cn = fg * cst[r] + ig * gg;
            cst[r] = cn;
            float h = og * tanhf_f(cn);
            hprev[r] = h;
            sh2[w][q * 4 + r][lm] = (bf16)h;
        }

        // 7. A-fragment-packed h store to slot s+1 via sc1 (lanes 0..31)
        if (l < 32) {
            int qq = l >> 4;                   // 0..1
            bf16x8 hv = *(const bf16x8*)(&sh2[w][lm][qq * 8]);
            int qp = qbase + qq;
            bf16* hAout = hA + (size_t)(s + 1) * 102400 + (size_t)d * 51200
                             + (size_t)(kt0 * 4 + w) * 512;
            store_b128_sc1(hAout + (size_t)(qp * 16 + lm) * 8, __builtin_bit_cast(u32x4, hv));
        }
        asm volatile("s_waitcnt vmcnt(0)" ::: "memory");
        if (l == 0)
            __hip_atomic_store(flags + myflag, s + 1, __ATOMIC_RELAXED, __HIP_MEMORY_SCOPE_AGENT);
    }

    // terminal barrier: deps reach 256, then aggregators publish epoch 256
    for (;;) {
        int a  = __hip_atomic_load(flags + fi1, __ATOMIC_RELAXED, __HIP_MEMORY_SCOPE_AGENT);
        int b2 = __hip_atomic_load(flags + fi2, __ATOMIC_RELAXED, __HIP_MEMORY_SCOPE_AGENT);
        if (__all((a >= 256) && (b2 >= 256))) break;
        __builtin_amdgcn_s_sleep(1);
    }
    if (isAgg && l == 0)
        __hip_atomic_store(flags + epOwn, 256, __ATOMIC_RELAXED, __HIP_MEMORY_SCOPE_AGENT);
    asm volatile("" ::: "memory");

#pragma unroll
    for (int r = 0; r < 4; ++r) {
        int b = w * 16 + q * 4 + r;
        out[((size_t)b * TDIM + 255) * 1600 + d * HDIM + jcol] = hprev[r];
        out[26214400u + (size_t)b * 1600 + d * HDIM + jcol] = hprev[r];
        out[26316800u + (size_t)b * 1600 + d * HDIM + jcol] = cst[r];
    }
}

// ---------------------------------------------------------------------------
extern "C" void kernel_launch(void* const* d_in, const int* in_sizes, int n_in,
                              void* d_out, int out_size, void* d_ws, size_t ws_size,
                              hipStream_t stream) {
    const float* x   = (const float*)d_in[0];
    const float* mf  = (const float*)d_in[1];
    const float* mb  = (const float*)d_in[2];
    const float* Wf  = (const float*)d_in[3];
    const float* Uf  = (const float*)d_in[4];
    const float* bf_ = (const float*)d_in[5];
    const float* Wb  = (const float*)d_in[6];
    const float* Ub  = (const float*)d_in[7];
    const float* bb_ = (const float*)d_in[8];

    if (ws_size < (size_t)WS_NEED) return;

    char*  ws    = (char*)d_ws;
    bf16*  upk   = (bf16*)(ws + OFF_UPK);
    bf16*  wpk   = (bf16*)(ws + OFF_WPK);
    bf16*  projb = (bf16*)(ws + OFF_PROJB);
    bf16*  hA    = (bf16*)(ws + OFF_HA);
    int*   flags = (int*)(ws + OFF_FLAGS);
    float* out   = (float*)d_out;
    bf16*  projf = (bf16*)d_out;    // fwd proj aliased into Hcat region

    static bool attr_set = false;
    if (!attr_set) {
        (void)hipFuncSetAttribute((const void*)krecur,
                                  hipFuncAttributeMaxDynamicSharedMemorySize, 51200);
        attr_set = true;
    }

    kinit<<<54, 256, 0, stream>>>((uint4*)(ws + OFF_HA), (uint4*)(ws + OFF_FLAGS));
    kpack<<<10000, 64, 0, stream>>>(Uf, Ub, upk, 25);
    kpack<<<6400, 64, 0, stream>>>(Wf, Wb, wpk, 16);
    kproj<<<2560, 256, 0, stream>>>(x, mf, mb, wpk, bf_, bb_, projf, projb);
    krecur<<<100, 256, 51200, stream>>>(upk, projf, projb, hA, flags, out);
}

// Round 15
// 1953.646 us; speedup vs baseline: 1.3138x; 1.3138x over previous
//
#include <hip/hip_runtime.h>

// ============================================================================
// Bidirectional LSTM (Keras-style), B=64 T=256 I=512 H=800, fp32 in/out.
//   K0  pack W/U -> bf16 MFMA B-fragment layout
//   K1  kproj: input projections (both dirs, bias folded), bf16 MFMA, row
//       layout [b][t][j*4+g]; proj_f ALIASED into d_out Hcat region.
//   K2  krecur: persistent kernel, 100 blocks x 4 waves (wave = batch tile mt).
//       U gates 0,1 pinned in regs (asm-opaque); gates 2,3 in LDS.
//       Sync (round-5 semantics + epoch aggregation): blocks jt==0 of each
//       direction direct-poll the 50/100 flag lines (as before) and publish a
//       per-wave-class EPOCH to one line; the other 98 blocks poll ONLY the
//       epoch line (wave-uniform, 1 line vs 50-100) -- cuts the L3 poll storm
//       ~50x. Epochs at ints 3200..3207 (past the 400-flag array).
//   ROUND 15: byte-for-byte restore of the round-9 build -- the best measured
//   total (1965 us). All subsequent kproj/krecur variants (r10-r14) were
//   null or negative within coupling/run noise; this locks in the optimum.
// ============================================================================

#define TDIM 256
#define IDIM 512
#define HDIM 800
#define H4   3200

typedef __bf16 bf16;
typedef __bf16 bf16x8 __attribute__((ext_vector_type(8)));
typedef __bf16 bf16x4 __attribute__((ext_vector_type(4)));
typedef float  f32x4  __attribute__((ext_vector_type(4)));
typedef unsigned int u32x4 __attribute__((ext_vector_type(4)));
typedef unsigned int u32x2 __attribute__((ext_vector_type(2)));

// workspace layout (bytes)
#define OFF_UPK   0ull            // 2*200*25*512 bf16 = 10,240,000
#define OFF_WPK   10240000ull     // 2*200*16*512 bf16 =  6,553,600
#define OFF_PROJB 16793600ull     // 64*256*3200 bf16  = 104,857,600
#define OFF_HA    121651200ull    // 257 slots * 204,800 B = 52,633,600
#define OFF_FLAGS 174284800ull    // 400 wave-flags * 32 B + epochs at int 3200..3207
#define WS_NEED   174297664ull    // = OFF_FLAGS + 12832 (12800 flags + 32 epochs)

__device__ __forceinline__ float sigf(float x)   { return 1.0f / (1.0f + __expf(-x)); }
__device__ __forceinline__ float tanhf_f(float x){ return 2.0f / (1.0f + __expf(-2.0f*x)) - 1.0f; }

__device__ __forceinline__ void store_b128_sc1(void* p, u32x4 v) {
    asm volatile("global_store_dwordx4 %0, %1, off sc1" :: "v"(p), "v"(v) : "memory");
}

// ---------------------------------------------------------------------------
// zero-init hA slot 0 (12,800 uint4) + flags/epochs (802 uint4)
__global__ __launch_bounds__(256) void kinit(uint4* __restrict__ ha0,
                                             uint4* __restrict__ flg) {
    int idx = blockIdx.x * 256 + threadIdx.x;
    if (idx < 12800) ha0[idx] = uint4{0u, 0u, 0u, 0u};
    else if (idx < 13602) flg[idx - 12800] = uint4{0u, 0u, 0u, 0u};
}

// ---------------------------------------------------------------------------
// pack fp32 [K][3200] weights into bf16 B-fragment tiles:
// tile (d, nt, kt): lane l holds S[kt*32 + (l>>4)*8 + j][nt*16 + (l&15)], j=0..7
__global__ __launch_bounds__(64) void kpack(const float* __restrict__ Sf,
                                            const float* __restrict__ Sb,
                                            bf16* __restrict__ dst, int nkt) {
    int bx = blockIdx.x;
    int kt = bx % nkt; int rest = bx / nkt;
    int nt = rest % 200; int d = rest / 200;
    const float* S = d ? Sb : Sf;
    int l  = threadIdx.x;
    int n  = nt * 16 + (l & 15);
    int k0 = kt * 32 + (l >> 4) * 8;
    bf16x8 v;
#pragma unroll
    for (int j = 0; j < 8; ++j) v[j] = (bf16)S[(size_t)(k0 + j) * H4 + n];
    *(bf16x8*)(dst + ((size_t)bx * 64 + l) * 8) = v;
}

// ---------------------------------------------------------------------------
// K1: proj row layout [b][t][j*4 + g], j in [0,800), g in [0,4).
// t_eff = s (fwd) or 255-s (bwd).  grid: d*5120 + b*80 + g*20 + tt*5 + jj
#define K1ROW 520
__global__ __launch_bounds__(256, 1) void kproj(
    const float* __restrict__ x, const float* __restrict__ mf, const float* __restrict__ mb,
    const bf16* __restrict__ wpk, const float* __restrict__ biasf, const float* __restrict__ biasb,
    bf16* __restrict__ projf, bf16* __restrict__ projb) {
    __shared__ bf16 sA[64 * K1ROW];

    int bx = blockIdx.x;
    int jj = bx % 5; int tt = (bx / 5) & 3; int g = (bx / 20) & 3;
    int b  = (bx / 80) & 63; int d = bx / 5120;

    int t  = threadIdx.x;
    int wv = t >> 6, l = t & 63;

    const float* mask = (d ? mb : mf) + (size_t)(b * 4 + g) * IDIM;
    int k = l * 8;
    float4 m0 = *(const float4*)(mask + k);
    float4 m1 = *(const float4*)(mask + k + 4);

    for (int it = 0; it < 16; ++it) {
        int trow = it * 4 + wv;
        int tg   = tt * 64 + trow;
        int te   = d ? (255 - tg) : tg;
        const float* xs = x + ((size_t)b * TDIM + te) * IDIM + k;
        float4 x0 = *(const float4*)xs;
        float4 x1 = *(const float4*)(xs + 4);
        bf16x8 v;
        v[0] = (bf16)(x0.x * m0.x); v[1] = (bf16)(x0.y * m0.y);
        v[2] = (bf16)(x0.z * m0.z); v[3] = (bf16)(x0.w * m0.w);
        v[4] = (bf16)(x1.x * m1.x); v[5] = (bf16)(x1.y * m1.y);
        v[6] = (bf16)(x1.z * m1.z); v[7] = (bf16)(x1.w * m1.w);
        *(bf16x8*)(&sA[trow * K1ROW + k]) = v;
    }
    __syncthreads();

    f32x4 acc[10];
#pragma unroll
    for (int nt = 0; nt < 10; ++nt) acc[nt] = f32x4{0.f, 0.f, 0.f, 0.f};

    int NTbase = g * 50 + jj * 10;
    const bf16* wb = wpk + ((size_t)d * 200 + NTbase) * 16 * 512 + l * 8;
    for (int kt = 0; kt < 16; ++kt) {
        bf16x8 a = *(const bf16x8*)(&sA[(wv * 16 + (l & 15)) * K1ROW + kt * 32 + (l >> 4) * 8]);
#pragma unroll
        for (int nt = 0; nt < 10; ++nt) {
            bf16x8 bw = *(const bf16x8*)(wb + ((size_t)nt * 16 + kt) * 512);
            acc[nt] = __builtin_amdgcn_mfma_f32_16x16x32_bf16(a, bw, acc[nt], 0, 0, 0);
        }
    }

    const float* bias = d ? biasb : biasf;
    bf16* dst = d ? projb : projf;
    int row0 = tt * 64 + wv * 16 + ((l >> 4) * 4);
#pragma unroll
    for (int nt = 0; nt < 10; ++nt) {
        int jr = jj * 160 + nt * 16 + (l & 15);
        float bv = bias[g * HDIM + jr];
#pragma unroll
        for (int r = 0; r < 4; ++r) {
            int trow = row0 + r;
            dst[((size_t)b * TDIM + trow) * H4 + (size_t)jr * 4 + g] = (bf16)(acc[nt][r] + bv);
        }
    }
}

// ---------------------------------------------------------------------------
// K2: persistent recurrence. grid = 100 x 256 (d = bx/50, jt = bx%50).
// Wave w (= mt) owns batch rows [w*16, w*16+16).
// hA slot layout: [slot][d][chunk=kt*4+mt][lane(64)][8] bf16 (A-fragment packed)
// flags: per (block, wave): flags[(bx*4 + w)*8], value = steps completed.
//        max flag index = 399*8 = 3192.
// epochs: flags[3200 + w] (fwd class-w), flags[3204 + w] (bwd class-w),
// published by the jt==0 block of each direction on its own gate-exit.
__global__ __launch_bounds__(256, 1) void krecur(
    const bf16* __restrict__ upk,
    const bf16* __restrict__ projf, const bf16* __restrict__ projb,
    bf16* __restrict__ hA, int* __restrict__ flags,
    float* __restrict__ out) {
    extern __shared__ char ldsraw[];
    bf16* uLds = (bf16*)ldsraw;        // gates 2,3: [2][25 kt][64 lane][8] = 51,200 B
    __shared__ bf16 sh2[4][16][24];    // per-wave h transpose (pad 24)

    int bx = blockIdx.x;
    int jt = bx % 50; int d = bx / 50;
    int tid = threadIdx.x;
    int w  = tid >> 6;                 // wave index == batch tile mt
    int l  = tid & 63;
    int lm = l & 15, q = l >> 4;
    int j0 = jt * 16;
    int jcol = j0 + lm;
    int kt0 = jt >> 1, qbase = (jt & 1) * 2;

    // ---- U gates 0,1 -> registers (asm-opaque: compiler cannot rematerialize)
    bf16x8 ureg[50];
#pragma unroll
    for (int g = 0; g < 2; ++g)
#pragma unroll
        for (int kt = 0; kt < 25; ++kt) {
            bf16x8 v = *(const bf16x8*)(
                upk + (((size_t)(d * 200 + g * 50 + jt)) * 25 + kt) * 512 + (size_t)l * 8);
            u32x4 u = __builtin_bit_cast(u32x4, v);
            asm volatile("" : "+v"(u));        // pin as opaque register value
            ureg[g * 25 + kt] = __builtin_bit_cast(bf16x8, u);
        }

    // ---- U gates 2,3 -> LDS (waves 0,1 stage; one-time)
    if (w < 2) {
        const bf16* ug = upk + (((size_t)(d * 200 + (w + 2) * 50 + jt)) * 25) * 512 + (size_t)l * 8;
        bf16* udst = uLds + (size_t)w * 25 * 512 + (size_t)l * 8;
#pragma unroll
        for (int kt = 0; kt < 25; ++kt) {
            bf16x8 v = *(const bf16x8*)(ug + (size_t)kt * 512);
            *(bf16x8*)(udst + (size_t)kt * 512) = v;
        }
    }
    __syncthreads();

    const char* prbase = (const char*)(d ? projb : projf);

    bool isAgg = (jt == 0);            // one aggregator block per direction
    int epOwn = 3200 + d * 4 + w;      // epoch line this block publishes (if agg)
    int f1, f2;
    int fi1, fi2;
    if (isAgg) {
        // aggregators direct-poll the flag lines (round-5 scheme)
        if (d == 0) { f1 = (l < 50) ? l : 49; f2 = f1; }      // fwd: 50 lines
        else        { f1 = l; f2 = (l < 36) ? (64 + l) : l; } // bwd: all 100
        fi1 = (f1 * 4 + w) * 8;
        fi2 = (f2 * 4 + w) * 8;
    } else {
        // consumers poll only the epoch line (wave-uniform, 1 cache line)
        fi1 = 3200 + w;                            // fwd epoch (h dep / alias guard)
        fi2 = (d == 0) ? (3200 + w) : (3204 + w);  // own-direction epoch
    }
    int myflag = (bx * 4 + w) * 8;

    float hprev[4], cst[4];
#pragma unroll
    for (int r = 0; r < 4; ++r) { hprev[r] = 0.f; cst[r] = 0.f; }

    size_t prOff = (size_t)j0 * 8 + (size_t)lm * 8;

#pragma unroll 1
    for (int s = 0; s < 256; ++s) {
        // 1. proj(s) loads for this wave's rows (nt; issued pre-gate, long slack)
        u32x2 pr[4];
#pragma unroll
        for (int r = 0; r < 4; ++r) {
            int b = w * 16 + q * 4 + r;
            pr[r] = __builtin_nontemporal_load(
                (const u32x2*)(prbase + ((size_t)b * TDIM + s) * 6400 + prOff));
        }

        // 2. spin until deps reach s (aggregator: flag lines; consumer: epochs)
        if (s > 0) {
            for (;;) {
                int a  = __hip_atomic_load(flags + fi1, __ATOMIC_RELAXED, __HIP_MEMORY_SCOPE_AGENT);
                int b2 = __hip_atomic_load(flags + fi2, __ATOMIC_RELAXED, __HIP_MEMORY_SCOPE_AGENT);
                if (__all((a >= s) && (b2 >= s))) break;
                __builtin_amdgcn_s_sleep(2);   // light backoff
            }
            if (isAgg && l == 0)               // publish class-w epoch
                __hip_atomic_store(flags + epOwn, s, __ATOMIC_RELAXED, __HIP_MEMORY_SCOPE_AGENT);
        }
        asm volatile("" ::: "memory");         // order af loads after spin-exit

        // 3. h A-fragments, chunks (kt, w): issue all 25 loads up front
        const bf16* hin = hA + (size_t)s * 102400 + (size_t)d * 51200
                             + (size_t)w * 512 + (size_t)l * 8;
        bf16x8 af[25];
#pragma unroll
        for (int kt = 0; kt < 25; ++kt)
            af[kt] = *(const bf16x8*)(hin + (size_t)kt * 2048);

        // 4. delayed Hcat write: row s-1 (nt streaming; after af issue)
        if (s > 0) {
#pragma unroll
            for (int r = 0; r < 4; ++r) {
                int b = w * 16 + q * 4 + r;
                __builtin_nontemporal_store(hprev[r],
                    &out[((size_t)b * TDIM + (s - 1)) * 1600 + d * HDIM + jcol]);
            }
        }

        // 5. MFMA: gates 0,1 B from registers; gates 2,3 B from LDS
        f32x4 acc[4];
#pragma unroll
        for (int g = 0; g < 4; ++g) acc[g] = f32x4{0.f, 0.f, 0.f, 0.f};

        const bf16* ul = uLds + (size_t)l * 8;
#pragma unroll
        for (int kt = 0; kt < 25; ++kt) {
            acc[0] = __builtin_amdgcn_mfma_f32_16x16x32_bf16(af[kt], ureg[kt],      acc[0], 0, 0, 0);
            acc[1] = __builtin_amdgcn_mfma_f32_16x16x32_bf16(af[kt], ureg[25 + kt], acc[1], 0, 0, 0);
            bf16x8 b2 = *(const bf16x8*)(ul + (size_t)kt * 512);
            bf16x8 b3 = *(const bf16x8*)(ul + (size_t)(25 + kt) * 512);
            acc[2] = __builtin_amdgcn_mfma_f32_16x16x32_bf16(af[kt], b2, acc[2], 0, 0, 0);
            acc[3] = __builtin_amdgcn_mfma_f32_16x16x32_bf16(af[kt], b3, acc[3], 0, 0, 0);
        }

        // 6. gates + state update; h -> per-wave LDS transpose
#pragma unroll
        for (int r = 0; r < 4; ++r) {
            bf16x4 p4 = __builtin_bit_cast(bf16x4, pr[r]);
            float zi = acc[0][r] + (float)p4[0];
            float zf = acc[1][r] + (float)p4[1];
            float zg = acc[2][r] + (float)p4[2];
            float zo = acc[3][r] + (float)p4[3];
            float ig = sigf(zi), fg = sigf(zf), gg = tanhf_f(zg), og = sigf(zo);
            float cn = fg * cst[r] + ig * gg;
            cst[r] = cn;
            float h = og * tanhf_f(cn);
            hprev[r] = h;
            sh2[w][q * 4 + r][lm] = (bf16)h;
        }

        // 7. A-fragment-packed h store to slot s+1 via sc1 (lanes 0..31)
        if (l < 32) {
            int qq = l >> 4;                   // 0..1
            bf16x8 hv = *(const bf16x8*)(&sh2[w][lm][qq * 8]);
            int qp = qbase + qq;
            bf16* hAout = hA + (size_t)(s + 1) * 102400 + (size_t)d * 51200
                             + (size_t)(kt0 * 4 + w) * 512;
            store_b128_sc1(hAout + (size_t)(qp * 16 + lm) * 8, __builtin_bit_cast(u32x4, hv));
        }
        asm volatile("s_waitcnt vmcnt(0)" ::: "memory");
        if (l == 0)
            __hip_atomic_store(flags + myflag, s + 1, __ATOMIC_RELAXED, __HIP_MEMORY_SCOPE_AGENT);
    }

    // terminal barrier: deps reach 256, then aggregators publish epoch 256
    for (;;) {
        int a  = __hip_atomic_load(flags + fi1, __ATOMIC_RELAXED, __HIP_MEMORY_SCOPE_AGENT);
        int b2 = __hip_atomic_load(flags + fi2, __ATOMIC_RELAXED, __HIP_MEMORY_SCOPE_AGENT);
        if (__all((a >= 256) && (b2 >= 256))) break;
        __builtin_amdgcn_s_sleep(2);
    }
    if (isAgg && l == 0)
        __hip_atomic_store(flags + epOwn, 256, __ATOMIC_RELAXED, __HIP_MEMORY_SCOPE_AGENT);
    asm volatile("" ::: "memory");

#pragma unroll
    for (int r = 0; r < 4; ++r) {
        int b = w * 16 + q * 4 + r;
        out[((size_t)b * TDIM + 255) * 1600 + d * HDIM + jcol] = hprev[r];
        out[26214400u + (size_t)b * 1600 + d * HDIM + jcol] = hprev[r];
        out[26316800u + (size_t)b * 1600 + d * HDIM + jcol] = cst[r];
    }
}

// ---------------------------------------------------------------------------
extern "C" void kernel_launch(void* const* d_in, const int* in_sizes, int n_in,
                              void* d_out, int out_size, void* d_ws, size_t ws_size,
                              hipStream_t stream) {
    const float* x   = (const float*)d_in[0];
    const float* mf  = (const float*)d_in[1];
    const float* mb  = (const float*)d_in[2];
    const float* Wf  = (const float*)d_in[3];
    const float* Uf  = (const float*)d_in[4];
    const float* bf_ = (const float*)d_in[5];
    const float* Wb  = (const float*)d_in[6];
    const float* Ub  = (const float*)d_in[7];
    const float* bb_ = (const float*)d_in[8];

    if (ws_size < (size_t)WS_NEED) return;

    char*  ws    = (char*)d_ws;
    bf16*  upk   = (bf16*)(ws + OFF_UPK);
    bf16*  wpk   = (bf16*)(ws + OFF_WPK);
    bf16*  projb = (bf16*)(ws + OFF_PROJB);
    bf16*  hA    = (bf16*)(ws + OFF_HA);
    int*   flags = (int*)(ws + OFF_FLAGS);
    float* out   = (float*)d_out;
    bf16*  projf = (bf16*)d_out;    // fwd proj aliased into Hcat region

    static bool attr_set = false;
    if (!attr_set) {
        (void)hipFuncSetAttribute((const void*)krecur,
                                  hipFuncAttributeMaxDynamicSharedMemorySize, 51200);
        attr_set = true;
    }

    kinit<<<54, 256, 0, stream>>>((uint4*)(ws + OFF_HA), (uint4*)(ws + OFF_FLAGS));
    kpack<<<10000, 64, 0, stream>>>(Uf, Ub, upk, 25);
    kpack<<<6400, 64, 0, stream>>>(Wf, Wb, wpk, 16);
    kproj<<<10240, 256, 0, stream>>>(x, mf, mb, wpk, bf_, bb_, projf, projb);
    krecur<<<100, 256, 51200, stream>>>(upk, projf, projb, hA, flags, out);
}